// Round 9
// baseline (1342.682 us; speedup 1.0000x reference)
//
#include <hip/hip_runtime.h>

// TitansMemory: per-row delta-rule-with-momentum scan. B=16, L=8192, DK=DV=128.
//   s = C_S*(w·k - v) ; m̂ = β m̂ + s k ; w = (1-α) w + m̂ ; y = w·q
// Mapping: TWO rows per wave (lanes 0-31 row0, 32-63 row1), 4 cols/lane (f4),
// 1024 single-wave blocks = 1 wave/SIMD. Pinned asm loads (r3-verified),
// 2-buffer A/B pipeline, WAITP-at-window-start, flushY-before-ISSUE
// (r4/r7-verified queue math; max 52 outstanding VMEM).
// Round 9 = round-8 SUB-WINDOW EXPANSION (W=4), resubmitted after infra
// failure (container died twice, no pytest traceback -> not kernel-caused).
// Closed form over 4 steps from state (W,M) at sub-window start:
//   w_{j-1} = A^j W + c_j M + sum_{i<j} phi_{j-1-i} s_i k_i
//   phi_d = (A^{d+1}-b^{d+1})/(A-b) ; c_j = b*phi_{j-1}       [compile-time]
//   s_j = base_j + sum_{i<j} (C_S*phi_{j-1-i}*G_ij) s_i
//   base_j = dot(C_S A^j W + C_S c_j M, k_j) + CV*v_j ; G_ij = k_i . k_j
// Per 8-chunk: 12 k-Grams (state-independent, issued right after WAITP) +
// 2 sub-windows x 4 fused U-dots. ALL reductions are independent bulk work
// (latency hidden by issue span); the serial part is a scalar triangular
// solve (critical path 4 fma) + the w/m applies (2 pk-fma/step).
// r7's failure mode (mkbase consumed 1 step after production -> full reduce2
// latency exposed every step, VALU busy-cyc/step 208 vs r3's 160) is gone.

#define L_ 8192
#define D_ 128

typedef __attribute__((ext_vector_type(4))) float f4;
typedef __attribute__((ext_vector_type(2))) float f2;
typedef __attribute__((ext_vector_type(2))) unsigned int u2;

constexpr float A_    = 0.98f;
constexpr float BETA_ = 0.9f;
constexpr float C_S   = -0.02f;       // -2*lr*(1-beta)
constexpr float CV_   = -C_S;

constexpr float PH1_  = A_ + BETA_;                           // phi_1
constexpr float PH2_  = A_ * A_ + A_ * BETA_ + BETA_ * BETA_; // phi_2
constexpr float T0_   = C_S;          // C_S*phi_0
constexpr float T1_   = C_S * PH1_;
constexpr float T2_   = C_S * PH2_;
constexpr float CSA0_ = C_S;                  // C_S*A^0
constexpr float CSA1_ = C_S * A_;
constexpr float CSA2_ = C_S * A_ * A_;
constexpr float CSA3_ = C_S * A_ * A_ * A_;
constexpr float CSC1_ = C_S * BETA_;          // C_S*c_1
constexpr float CSC2_ = C_S * BETA_ * PH1_;   // C_S*c_2
constexpr float CSC3_ = C_S * BETA_ * PH2_;   // C_S*c_3

template <int CTRL>
__device__ __forceinline__ float dpp_add(float x) {
  int y = __builtin_amdgcn_update_dpp(0, __float_as_int(x), CTRL, 0xF, 0xF, true);
  return x + __int_as_float(y);
}

__device__ __forceinline__ float fold4(f4 d) {
  f2 t = {d.x + d.z, d.y + d.w};
  return t.x + t.y;
}

__device__ __forceinline__ u2 swap16(float a, float b) {
  return __builtin_amdgcn_permlane16_swap(__float_as_uint(a), __float_as_uint(b),
                                          false, false);
}

// Dual 32-lane reduce: {sum32(a), sum32(b)} valid in EVERY lane of each half.
// (Semantics harness-verified r1/r2/r4/r7.)
__device__ __forceinline__ f2 reduce2(float a, float b) {
  u2 r = swap16(a, b);
  float c = __uint_as_float(r.x) + __uint_as_float(r.y);
  c = dpp_add<0x121>(c);
  c = dpp_add<0x122>(c);
  c = dpp_add<0x124>(c);
  c = dpp_add<0x128>(c);
  u2 u = swap16(c, c);
  return {__uint_as_float(u.x), __uint_as_float(u.y)};
}

// Pinned loads: asm volatile keeps issue placement and register residency.
#define GLD4(dst, addr, OFF) \
  asm volatile("global_load_dwordx4 %0, %1, off offset:" OFF : "=v"(dst) : "v"(addr))
#define GLD1(dst, addr, OFF) \
  asm volatile("global_load_dword %0, %1, off offset:" OFF : "=v"(dst) : "v"(addr))

#define ISSUE_CHUNK(kb, qb, vb)                            \
  do {                                                     \
    GLD4(kb[0], ka64, "0");    GLD4(qb[0], qa64, "0");    GLD1(vb[0], va64, "0");    \
    GLD4(kb[1], ka64, "512");  GLD4(qb[1], qa64, "512");  GLD1(vb[1], va64, "512");  \
    GLD4(kb[2], ka64, "1024"); GLD4(qb[2], qa64, "1024"); GLD1(vb[2], va64, "1024"); \
    GLD4(kb[3], ka64, "1536"); GLD4(qb[3], qa64, "1536"); GLD1(vb[3], va64, "1536"); \
    GLD4(kb[4], ka64, "2048"); GLD4(qb[4], qa64, "2048"); GLD1(vb[4], va64, "2048"); \
    GLD4(kb[5], ka64, "2560"); GLD4(qb[5], qa64, "2560"); GLD1(vb[5], va64, "2560"); \
    GLD4(kb[6], ka64, "3072"); GLD4(qb[6], qa64, "3072"); GLD1(vb[6], va64, "3072"); \
    GLD4(kb[7], ka64, "3584"); GLD4(qb[7], qa64, "3584"); GLD1(vb[7], va64, "3584"); \
    uint64_t bump_ = (sc < 1023) ? 4096u : 0u;             \
    ka64 += bump_; qa64 += bump_; va64 += bump_; ++sc;     \
  } while (0)

#define WAITP                                              \
  do {                                                     \
    asm volatile("s_waitcnt vmcnt(24)");                   \
    __builtin_amdgcn_sched_barrier(0);                     \
  } while (0)

// One 4-step sub-window at literal offset O within the chunk. All array
// indices are compile-time constants (rule #20: no scratch).
#define SUBWIN(kX, qX, vX, O, G)                                         \
  do {                                                                   \
    f4 u0 = vcsa0 * w;                                                   \
    f4 u1 = __builtin_elementwise_fma(vcsa1, w, vcsc1 * m);              \
    f4 u2 = __builtin_elementwise_fma(vcsa2, w, vcsc2 * m);              \
    f4 u3 = __builtin_elementwise_fma(vcsa3, w, vcsc3 * m);              \
    f2 d01 = reduce2(fold4(u0 * kX[O + 0]), fold4(u1 * kX[O + 1]));      \
    f2 d23 = reduce2(fold4(u2 * kX[O + 2]), fold4(u3 * kX[O + 3]));      \
    float b0 = fmaf(CV_, vX[O + 0], d01.x);                              \
    float b1 = fmaf(CV_, vX[O + 1], d01.y);                              \
    float b2 = fmaf(CV_, vX[O + 2], d23.x);                              \
    float b3 = fmaf(CV_, vX[O + 3], d23.y);                              \
    float s0 = b0;                                                       \
    float s1 = fmaf(T0_ * G[0], s0, b1);                                 \
    float s2 = fmaf(T0_ * G[3], s1, fmaf(T1_ * G[1], s0, b2));           \
    float s3 = fmaf(T0_ * G[5], s2,                                      \
                fmaf(T1_ * G[4], s1, fmaf(T2_ * G[2], s0, b3)));         \
    apply(s0, kX[O + 0], qX[O + 0], ey[O + 0]);                          \
    apply(s1, kX[O + 1], qX[O + 1], ey[O + 1]);                          \
    apply(s2, kX[O + 2], qX[O + 2], ey[O + 2]);                          \
    apply(s3, kX[O + 3], qX[O + 3], ey[O + 3]);                          \
  } while (0)

__global__ __launch_bounds__(64, 1)
void TitansMemory_188978561365_kernel(const float* __restrict__ Q,
                                      const float* __restrict__ K,
                                      const float* __restrict__ V,
                                      float* __restrict__ Y) {
  const int lane  = threadIdx.x;              // 0..63
  const int wid   = blockIdx.x;               // 0..1023
  const int batch = wid >> 6;                 // 64 waves per batch (128 rows)
  const int col   = (lane & 31) << 2;         // 4 k-cols per lane

  const size_t bbase = (size_t)batch * (size_t)L_ * D_;
  uint64_t ka64 = (uint64_t)(K + bbase + col);
  uint64_t qa64 = (uint64_t)(Q + bbase + col);
  uint64_t va64 = (uint64_t)(V + bbase + ((wid & 63) << 1) + (lane >> 5));
  // y store base (r4-verified): 16-group g holds (row=g>>1, t-parity=g&1);
  // lanes 0,16,32,48 store.
  float* yb = Y + bbase + ((wid & 63) << 1) + (lane >> 5)
                + (size_t)((lane >> 4) & 1) * D_;
  int sc = 0;  // chunks issued (tail clamp)

  const f4 av = {A_, A_, A_, A_};
  const f4 bv = {BETA_, BETA_, BETA_, BETA_};
  const f4 vcsa0 = {CSA0_, CSA0_, CSA0_, CSA0_};
  const f4 vcsa1 = {CSA1_, CSA1_, CSA1_, CSA1_};
  const f4 vcsa2 = {CSA2_, CSA2_, CSA2_, CSA2_};
  const f4 vcsa3 = {CSA3_, CSA3_, CSA3_, CSA3_};
  const f4 vcsc1 = {CSC1_, CSC1_, CSC1_, CSC1_};
  const f4 vcsc2 = {CSC2_, CSC2_, CSC2_, CSC2_};
  const f4 vcsc3 = {CSC3_, CSC3_, CSC3_, CSC3_};

  f4 w = {0.f, 0.f, 0.f, 0.f}, m = {0.f, 0.f, 0.f, 0.f};
  float ey[8];

  f4 kA[8], qA[8]; float vA[8];
  f4 kB[8], qB[8]; float vB[8];

  // Apply one step with final s: update m,w; stash exact y partial.
  auto apply = [&](float s, const f4& kj, const f4& qj, float& eyj) {
    f4 s4 = {s, s, s, s};
    m = __builtin_elementwise_fma(s4, kj, bv * m);
    w = __builtin_elementwise_fma(av, w, m);
    eyj = fold4(w * qj);
  };

  auto chunk = [&](f4 (&kX)[8], f4 (&qX)[8], float (&vX)[8]) {
    // ---- 12 k-Grams (state-independent; issued first, consumed late) ----
    float Ga[6], Gb[6];  // order: G01,G02,G03,G12,G13,G23 (relative indices)
    {
      f2 gA = reduce2(fold4(kX[0] * kX[1]), fold4(kX[0] * kX[2]));
      f2 gB = reduce2(fold4(kX[0] * kX[3]), fold4(kX[1] * kX[2]));
      f2 gC = reduce2(fold4(kX[1] * kX[3]), fold4(kX[2] * kX[3]));
      Ga[0] = gA.x; Ga[1] = gA.y; Ga[2] = gB.x;
      Ga[3] = gB.y; Ga[4] = gC.x; Ga[5] = gC.y;
      f2 gD = reduce2(fold4(kX[4] * kX[5]), fold4(kX[4] * kX[6]));
      f2 gE = reduce2(fold4(kX[4] * kX[7]), fold4(kX[5] * kX[6]));
      f2 gF = reduce2(fold4(kX[5] * kX[7]), fold4(kX[6] * kX[7]));
      Gb[0] = gD.x; Gb[1] = gD.y; Gb[2] = gE.x;
      Gb[3] = gE.y; Gb[4] = gF.x; Gb[5] = gF.y;
    }
    SUBWIN(kX, qX, vX, 0, Ga);
    SUBWIN(kX, qX, vX, 4, Gb);
    // ---- deferred y: 4 pair-reduces + predicated stores (r4-verified) ----
#pragma unroll
    for (int p = 0; p < 4; ++p) {
      u2 r = swap16(ey[2 * p], ey[2 * p + 1]);
      float c = __uint_as_float(r.x) + __uint_as_float(r.y);
      c = dpp_add<0x121>(c);
      c = dpp_add<0x122>(c);
      c = dpp_add<0x124>(c);
      c = dpp_add<0x128>(c);
      if ((lane & 15) == 0) yb[(size_t)(2 * p) * D_] = c;
    }
    yb += 8 * D_;
    ISSUE_CHUNK(kX, qX, vX);   // refill this buffer (chunk c+2)
  };

  // Prologue: two chunks in flight (48 loads; max outstanding anywhere = 52).
  ISSUE_CHUNK(kA, qA, vA);
  ISSUE_CHUNK(kB, qB, vB);

  for (int it = 0; it < 512; ++it) {   // 1024 chunks of 8 steps
    WAITP;                             // A-chunk resident
    chunk(kA, qA, vA);
    WAITP;                             // B-chunk resident
    chunk(kB, qB, vB);
  }
}

extern "C" void kernel_launch(void* const* d_in, const int* in_sizes, int n_in,
                              void* d_out, int out_size, void* d_ws, size_t ws_size,
                              hipStream_t stream) {
  const float* Q = (const float*)d_in[0];
  const float* K = (const float*)d_in[1];
  const float* V = (const float*)d_in[2];
  float* Y = (float*)d_out;
  dim3 grid(1024), block(64);
  hipLaunchKernelGGL(TitansMemory_188978561365_kernel, grid, block, 0, stream,
                     Q, K, V, Y);
}